// Round 1
// baseline (349.875 us; speedup 1.0000x reference)
//
#include <hip/hip_runtime.h>

// SIREN fused MLP: 262144 pts, 3->128, 7x residual(sin) blocks, 128->1.
// Strategy: all 15 layers fused in one kernel; h-tile (128 pts) lives in LDS
// (bf16, for MFMA A-frags) + f32 residual held in registers (C-frag layout).
// Weights staged per-layer into double-buffered LDS (bf16, scaled by
// omega*w1/2pi so epilogue = v_sin(fract(acc)) directly).
#define NPTS 262144
#define HID  128
#define NB   7

typedef __attribute__((ext_vector_type(8))) short bf16x8;
typedef __attribute__((ext_vector_type(4))) float f32x4;

constexpr float OMEGA  = 30.0f;
constexpr float INV2PI = 0.15915494309189535f;

#define LDS_BYTES 147456
// LDS map (bytes):
//   hs   @      0  [128][136] bf16  34816   h tile (A operand)
//   s1s  @  34816  [128][136] bf16  34816   s1 tile
//   wsA  @  69632  [128][136] bf16  34816   weight buffer A
//   wsB  @ 104448  [128][136] bf16  34816   weight buffer B
//   bsc  @ 139264  [14][128] f32     7168   pre-scaled biases
//   red  @ 146432  [128][2]  f32     1024   final-layer reduction

__device__ __forceinline__ unsigned short f2bf(float v) {
    unsigned int u = __float_as_uint(v);
    u += 0x7fffu + ((u >> 16) & 1u);          // RNE
    return (unsigned short)(u >> 16);
}

__device__ __forceinline__ float sin_rev(float r) {
    // sin(2*pi*r); v_fract for exact periodic reduction, then v_sin
    return __builtin_amdgcn_sinf(__builtin_amdgcn_fractf(r));
}

__launch_bounds__(512, 2)
__global__ void siren_fused(const float* __restrict__ x,
                            const float* __restrict__ W0,
                            const float* __restrict__ b0,
                            const float* __restrict__ Wa,
                            const float* __restrict__ ba,
                            const float* __restrict__ Wb,
                            const float* __restrict__ bb,
                            const float* __restrict__ Wf,
                            const float* __restrict__ bfin,
                            float* __restrict__ out) {
    extern __shared__ char smem[];
    unsigned short* hs  = (unsigned short*)(smem);
    unsigned short* s1s = (unsigned short*)(smem + 34816);
    unsigned short* wsA = (unsigned short*)(smem + 69632);
    unsigned short* wsB = (unsigned short*)(smem + 104448);
    float*          bsc = (float*)(smem + 139264);
    float*          red = (float*)(smem + 146432);

    const int tid  = threadIdx.x;
    const int lane = tid & 63;
    const int w    = tid >> 6;       // wave 0..7
    const int wm   = w >> 1;         // 0..3 : point-block  (32 pts)
    const int wn   = w & 1;          // 0..1 : out-block    (64 outs)
    const int l16  = lane & 15;
    const int lhi  = lane >> 4;      // 0..3

    const int rowA0 = 32*wm + l16;   // A-frag row (mh=0)
    const int colB0 = 64*wn + l16;   // B-frag row base (+16*nh)

    // weight staging assignment: thread stages row srow, 32 cols at scol
    const int srow = tid >> 2;
    const int scol = (tid & 3) * 32;
    const float bscale = OMEGA * INV2PI;

    // ---- issue Wa[0] global loads early ----
    f32x4 wreg[8];
    {
        const f32x4* g = (const f32x4*)(Wa + srow*HID + scol);
        #pragma unroll
        for (int q = 0; q < 8; ++q) wreg[q] = g[q];
    }

    // ---- stage pre-scaled biases (omega/2pi * b) ----
    for (int e = tid; e < 14*HID; e += 512) {
        float v = (e < 7*HID) ? ba[e] : bb[e - 7*HID];
        bsc[e] = v * bscale;
    }

    // ---- first layer: h = sin(omega*(x@W0^T + b0)), fp32 VALU ----
    f32x4 resid[2][4];   // f32 residual, C-frag layout [mh][nh][r]
    {
        float w0r[4][3], b0r[4];
        #pragma unroll
        for (int nh = 0; nh < 4; ++nh) {
            int i = colB0 + 16*nh;
            w0r[nh][0] = W0[3*i+0]; w0r[nh][1] = W0[3*i+1]; w0r[nh][2] = W0[3*i+2];
            b0r[nh]    = b0[i];
        }
        #pragma unroll
        for (int mh = 0; mh < 2; ++mh)
            #pragma unroll
            for (int r = 0; r < 4; ++r) {
                int pl = 32*wm + 16*mh + 4*lhi + r;
                int pg = blockIdx.x * 128 + pl;
                float x0 = x[3*pg], x1 = x[3*pg+1], x2 = x[3*pg+2];
                #pragma unroll
                for (int nh = 0; nh < 4; ++nh) {
                    float arg = (x0*w0r[nh][0] + x1*w0r[nh][1] + x2*w0r[nh][2]
                                 + b0r[nh]) * bscale;
                    float h0 = sin_rev(arg);
                    resid[mh][nh][r] = h0;
                    hs[pl*136 + colB0 + 16*nh] = f2bf(h0);
                }
            }
    }

    // ---- write wsA = (omega/2pi)*Wa[0]  (w1=1 for block 0) ----
    {
        unsigned short* dst = wsA + srow*136 + scol;
        #pragma unroll
        for (int q = 0; q < 8; ++q)
            #pragma unroll
            for (int e = 0; e < 4; ++e) dst[q*4+e] = f2bf(wreg[q][e] * bscale);
    }
    __syncthreads();

    // ---- 7 residual blocks ----
    for (int blk = 0; blk < NB; ++blk) {
        // issue Wb[blk] loads (hide under matmul1)
        {
            const f32x4* g = (const f32x4*)(Wb + blk*HID*HID + srow*HID + scol);
            #pragma unroll
            for (int q = 0; q < 8; ++q) wreg[q] = g[q];
        }

        // matmul1: acc = bias' + h @ Wa'^T
        f32x4 acc[2][4];
        const float* bias1 = bsc + blk*HID;
        #pragma unroll
        for (int mh = 0; mh < 2; ++mh)
            #pragma unroll
            for (int nh = 0; nh < 4; ++nh) {
                float bv = bias1[colB0 + 16*nh];
                acc[mh][nh] = (f32x4){bv, bv, bv, bv};
            }
        #pragma unroll
        for (int ks = 0; ks < 4; ++ks) {
            int ko = ks*32 + lhi*8;
            bf16x8 a0 = *(const bf16x8*)(hs + rowA0*136 + ko);
            bf16x8 a1 = *(const bf16x8*)(hs + (rowA0+16)*136 + ko);
            #pragma unroll
            for (int nh = 0; nh < 4; ++nh) {
                bf16x8 b = *(const bf16x8*)(wsA + (colB0 + 16*nh)*136 + ko);
                acc[0][nh] = __builtin_amdgcn_mfma_f32_16x16x32_bf16(a0, b, acc[0][nh], 0, 0, 0);
                acc[1][nh] = __builtin_amdgcn_mfma_f32_16x16x32_bf16(a1, b, acc[1][nh], 0, 0, 0);
            }
        }
        // epilogue1: s1 = sin(acc) -> s1s (bf16)
        #pragma unroll
        for (int mh = 0; mh < 2; ++mh)
            #pragma unroll
            for (int nh = 0; nh < 4; ++nh)
                #pragma unroll
                for (int r = 0; r < 4; ++r) {
                    float s = sin_rev(acc[mh][nh][r]);
                    s1s[(32*wm + 16*mh + 4*lhi + r)*136 + colB0 + 16*nh] = f2bf(s);
                }
        // write wsB = (omega/2pi)*Wb[blk]
        {
            unsigned short* dst = wsB + srow*136 + scol;
            #pragma unroll
            for (int q = 0; q < 8; ++q)
                #pragma unroll
                for (int e = 0; e < 4; ++e) dst[q*4+e] = f2bf(wreg[q][e] * bscale);
        }
        __syncthreads();

        // issue Wa[blk+1] loads (hide under matmul2)
        if (blk < NB-1) {
            const f32x4* g = (const f32x4*)(Wa + (blk+1)*HID*HID + srow*HID + scol);
            #pragma unroll
            for (int q = 0; q < 8; ++q) wreg[q] = g[q];
        }

        // matmul2: acc = bias' + s1 @ Wb'^T
        const float* bias2 = bsc + (7+blk)*HID;
        #pragma unroll
        for (int mh = 0; mh < 2; ++mh)
            #pragma unroll
            for (int nh = 0; nh < 4; ++nh) {
                float bv = bias2[colB0 + 16*nh];
                acc[mh][nh] = (f32x4){bv, bv, bv, bv};
            }
        #pragma unroll
        for (int ks = 0; ks < 4; ++ks) {
            int ko = ks*32 + lhi*8;
            bf16x8 a0 = *(const bf16x8*)(s1s + rowA0*136 + ko);
            bf16x8 a1 = *(const bf16x8*)(s1s + (rowA0+16)*136 + ko);
            #pragma unroll
            for (int nh = 0; nh < 4; ++nh) {
                bf16x8 b = *(const bf16x8*)(wsB + (colB0 + 16*nh)*136 + ko);
                acc[0][nh] = __builtin_amdgcn_mfma_f32_16x16x32_bf16(a0, b, acc[0][nh], 0, 0, 0);
                acc[1][nh] = __builtin_amdgcn_mfma_f32_16x16x32_bf16(a1, b, acc[1][nh], 0, 0, 0);
            }
        }
        // epilogue2: h = w2*(h + sin(acc)); residual stays f32 in regs
        const float w2 = (blk == NB-1) ? 0.5f : 1.0f;
        #pragma unroll
        for (int mh = 0; mh < 2; ++mh)
            #pragma unroll
            for (int nh = 0; nh < 4; ++nh)
                #pragma unroll
                for (int r = 0; r < 4; ++r) {
                    float s2 = sin_rev(acc[mh][nh][r]);
                    float hn = w2 * (resid[mh][nh][r] + s2);
                    resid[mh][nh][r] = hn;
                    if (blk < NB-1)
                        hs[(32*wm + 16*mh + 4*lhi + r)*136 + colB0 + 16*nh] = f2bf(hn);
                }
        // write wsA = (0.5*omega/2pi)*Wa[blk+1]   (w1=0.5 for blk>=1)
        if (blk < NB-1) {
            unsigned short* dst = wsA + srow*136 + scol;
            #pragma unroll
            for (int q = 0; q < 8; ++q)
                #pragma unroll
                for (int e = 0; e < 4; ++e) dst[q*4+e] = f2bf(wreg[q][e] * (0.5f * bscale));
        }
        __syncthreads();
    }

    // ---- final linear: out = h @ Wf^T + bf  (fp32, shuffle reduce) ----
    {
        float wf[4];
        #pragma unroll
        for (int nh = 0; nh < 4; ++nh) wf[nh] = Wf[colB0 + 16*nh];
        #pragma unroll
        for (int mh = 0; mh < 2; ++mh)
            #pragma unroll
            for (int r = 0; r < 4; ++r) {
                float part = resid[mh][0][r]*wf[0] + resid[mh][1][r]*wf[1]
                           + resid[mh][2][r]*wf[2] + resid[mh][3][r]*wf[3];
                part += __shfl_xor(part, 1);
                part += __shfl_xor(part, 2);
                part += __shfl_xor(part, 4);
                part += __shfl_xor(part, 8);
                if (l16 == 0)
                    red[(32*wm + 16*mh + 4*lhi + r)*2 + wn] = part;
            }
    }
    __syncthreads();
    if (tid < 128)
        out[blockIdx.x * 128 + tid] = red[tid*2] + red[tid*2+1] + bfin[0];
}

extern "C" void kernel_launch(void* const* d_in, const int* in_sizes, int n_in,
                              void* d_out, int out_size, void* d_ws, size_t ws_size,
                              hipStream_t stream) {
    const float* x   = (const float*)d_in[0];
    const float* W0  = (const float*)d_in[1];
    const float* b0  = (const float*)d_in[2];
    const float* Wa  = (const float*)d_in[3];
    const float* ba  = (const float*)d_in[4];
    const float* Wb  = (const float*)d_in[5];
    const float* bb  = (const float*)d_in[6];
    const float* Wf  = (const float*)d_in[7];
    const float* bf_ = (const float*)d_in[8];

    hipFuncSetAttribute(reinterpret_cast<const void*>(siren_fused),
                        hipFuncAttributeMaxDynamicSharedMemorySize, LDS_BYTES);
    siren_fused<<<dim3(NPTS/128), dim3(512), LDS_BYTES, stream>>>(
        x, W0, b0, Wa, ba, Wb, bb, Wf, bf_, (float*)d_out);
}

// Round 2
// 152.788 us; speedup vs baseline: 2.2899x; 2.2899x over previous
//
#include <hip/hip_runtime.h>

// SIREN fused MLP, swapped-operand register-resident design.
// D[feat][pt] = W·act: MFMA C-layout slot (t,g,r) at lane (g,l16) feeds the
// next matmul's B-fragment at the SAME lane under input-column permutation
//   kappa(f) = 32*(t>>1) + 8*g + 4*(t&1) + r   (f = 16t+4g+r)
// which is baked into the weight image by a prep kernel (plus bf16 convert,
// omega*w1/2pi scale, and (row&7)<<4 XOR bank swizzle). Activations/residual
// live entirely in registers; LDS carries only weights (dbuf) + biases.
#define NPTS 262144
#define HID  128
#define NB   7
#define NMAT 14

typedef __attribute__((ext_vector_type(8))) short bf16x8;
typedef __attribute__((ext_vector_type(4))) float f32x4;
typedef __attribute__((ext_vector_type(4))) unsigned int u32x4;

constexpr float OMEGA  = 30.0f;
constexpr float INV2PI = 0.15915494309189535f;

#define WIMG_BYTES (NMAT*32768)   // 458752
#define BIAS_ELEMS (NMAT*128)     // 1792 f32, prescaled
__device__ __align__(16) unsigned char g_img[WIMG_BYTES + BIAS_ELEMS*4];

__device__ __forceinline__ unsigned short f2bf(float v) {
    unsigned int u = __float_as_uint(v);
    u += 0x7fffu + ((u >> 16) & 1u);          // RNE
    return (unsigned short)(u >> 16);
}

__device__ __forceinline__ float sin_rev(float r) {
    // sin(2*pi*r): v_fract (exact periodic reduce) + v_sin (revolutions)
    return __builtin_amdgcn_sinf(__builtin_amdgcn_fractf(r));
}

__device__ __forceinline__ unsigned int cvtpk(float lo, float hi) {
    unsigned int r;
    asm("v_cvt_pk_bf16_f32 %0, %1, %2" : "=v"(r) : "v"(lo), "v"(hi));
    return r;
}

// ---- prep: bake scaled/permuted/swizzled bf16 weight image + biases ----
__global__ void prep(const float* __restrict__ Wa, const float* __restrict__ ba,
                     const float* __restrict__ Wb, const float* __restrict__ bb) {
    int idx = blockIdx.x * 256 + threadIdx.x;
    const float bscale = OMEGA * INV2PI;
    const int total = NMAT * HID * HID;
    if (idx < total) {
        int mi = idx >> 14, rc = idx & 16383;
        int row = rc >> 7, col = rc & 127;
        int l = mi >> 1;
        float sc = bscale, v;
        if (mi & 1) v = Wb[l*16384 + rc];
        else { v = Wa[l*16384 + rc]; if (l > 0) sc *= 0.5f; }   // w1=0.5, blk>0
        int t = col >> 4, g = (col >> 2) & 3, r = col & 3;
        int kp = ((t >> 1) << 5) | (g << 3) | ((t & 1) << 2) | r;
        int byte = mi*32768 + row*256 + ((kp*2) ^ ((row & 7) << 4));
        *(unsigned short*)(g_img + byte) = f2bf(v * sc);
    } else if (idx < total + BIAS_ELEMS) {
        int e = idx - total;
        int j = e >> 7, f = e & 127, l = j >> 1;
        float v = (j & 1) ? bb[l*HID + f] : ba[l*HID + f];
        ((float*)(g_img + WIMG_BYTES))[e] = v * bscale;
    }
}

// ---- main: 8 waves x 32 pts = 256 pts/block; LDS = Wdbuf(64K)+bias(7K) ----
#define LDS_BYTES 72704

__launch_bounds__(512, 2)
__global__ void siren_mlp(const float* __restrict__ x,
                          const float* __restrict__ W0,
                          const float* __restrict__ b0,
                          const float* __restrict__ Wf,
                          const float* __restrict__ bfin,
                          float* __restrict__ out) {
    extern __shared__ char smem[];          // buf0 @0, buf1 @32768, bsc @65536
    float* bsc = (float*)(smem + 65536);

    const int tid  = threadIdx.x;
    const int lane = tid & 63;
    const int w    = tid >> 6;
    const int l16  = lane & 15;
    const int g    = lane >> 4;
    const int swz  = (l16 & 7) << 4;
    const int ptb  = blockIdx.x * 256 + w * 32;
    const float bscale = OMEGA * INV2PI;

    u32x4 st[4];
    // issue matrix-0 + bias loads early (hide under first layer)
    {
        const u32x4* gp = (const u32x4*)(g_img);
        #pragma unroll
        for (int i = 0; i < 4; ++i) st[i] = gp[w*256 + i*64 + lane];
    }
    u32x4 bld;
    if (tid < 448) bld = ((const u32x4*)(g_img + WIMG_BYTES))[tid];

    // ---- first layer: h = sin(omega*(x@W0^T+b0)), f32 VALU, acc-order ----
    f32x4 resid[2][8];
    #pragma unroll
    for (int s = 0; s < 2; ++s) {
        int pt = ptb + 16*s + l16;
        float x0 = x[3*pt], x1 = x[3*pt+1], x2 = x[3*pt+2];
        #pragma unroll
        for (int t = 0; t < 8; ++t)
            #pragma unroll
            for (int r = 0; r < 4; ++r) {
                int f = 16*t + 4*g + r;
                float arg = (x0*W0[3*f] + x1*W0[3*f+1] + x2*W0[3*f+2] + b0[f]) * bscale;
                resid[s][t][r] = sin_rev(arg);
            }
    }
    {
        u32x4* lp = (u32x4*)smem;
        #pragma unroll
        for (int i = 0; i < 4; ++i) lp[w*256 + i*64 + lane] = st[i];
        if (tid < 448) ((u32x4*)bsc)[tid] = bld;
    }
    __syncthreads();

    unsigned int bfr[2][4][4];
    f32x4 acc[2][8];

    #pragma unroll 1
    for (int blk = 0; blk < NB; ++blk) {
        // B-frags for matmul1 from resid (pure in-register relayout)
        #pragma unroll
        for (int s = 0; s < 2; ++s)
            #pragma unroll
            for (int t = 0; t < 8; ++t) {
                bfr[s][t>>1][(t&1)*2]   = cvtpk(resid[s][t][0], resid[s][t][1]);
                bfr[s][t>>1][(t&1)*2+1] = cvtpk(resid[s][t][2], resid[s][t][3]);
            }
        // issue stage of matrix 2blk+1 (lands in buf1 before mid-barrier)
        {
            const u32x4* gp = (const u32x4*)(g_img + (2*blk+1)*32768);
            #pragma unroll
            for (int i = 0; i < 4; ++i) st[i] = gp[w*256 + i*64 + lane];
        }
        // ---- matmul1: acc = b' + Wa'·h  (A from buf0) ----
        {
            const float* bj = bsc + (2*blk)*128;
            #pragma unroll
            for (int t = 0; t < 8; ++t) {
                f32x4 bv = *(const f32x4*)(bj + 16*t + 4*g);
                acc[0][t] = bv; acc[1][t] = bv;
            }
            const char* wb = smem;
            #pragma unroll
            for (int ks = 0; ks < 4; ++ks) {
                u32x4 u0 = {bfr[0][ks][0], bfr[0][ks][1], bfr[0][ks][2], bfr[0][ks][3]};
                u32x4 u1 = {bfr[1][ks][0], bfr[1][ks][1], bfr[1][ks][2], bfr[1][ks][3]};
                bf16x8 bf0 = __builtin_bit_cast(bf16x8, u0);
                bf16x8 bf1 = __builtin_bit_cast(bf16x8, u1);
                #pragma unroll
                for (int t = 0; t < 8; ++t) {
                    bf16x8 a = *(const bf16x8*)(wb + (16*t + l16)*256 + ((64*ks + 16*g) ^ swz));
                    acc[0][t] = __builtin_amdgcn_mfma_f32_16x16x32_bf16(a, bf0, acc[0][t], 0,0,0);
                    acc[1][t] = __builtin_amdgcn_mfma_f32_16x16x32_bf16(a, bf1, acc[1][t], 0,0,0);
                }
            }
        }
        // epilogue1: s1 = sin(acc) -> B-frags for matmul2
        #pragma unroll
        for (int s = 0; s < 2; ++s)
            #pragma unroll
            for (int t = 0; t < 8; ++t) {
                float v0 = sin_rev(acc[s][t][0]);
                float v1 = sin_rev(acc[s][t][1]);
                float v2 = sin_rev(acc[s][t][2]);
                float v3 = sin_rev(acc[s][t][3]);
                bfr[s][t>>1][(t&1)*2]   = cvtpk(v0, v1);
                bfr[s][t>>1][(t&1)*2+1] = cvtpk(v2, v3);
            }
        // write staged matrix into buf1
        {
            u32x4* lp = (u32x4*)(smem + 32768);
            #pragma unroll
            for (int i = 0; i < 4; ++i) lp[w*256 + i*64 + lane] = st[i];
        }
        __syncthreads();
        // issue stage of matrix 2blk+2 (for next blk's matmul1, into buf0)
        if (blk < NB-1) {
            const u32x4* gp = (const u32x4*)(g_img + (2*blk+2)*32768);
            #pragma unroll
            for (int i = 0; i < 4; ++i) st[i] = gp[w*256 + i*64 + lane];
        }
        // ---- matmul2: acc = b' + Wb'·s1  (A from buf1) ----
        {
            const float* bj = bsc + (2*blk+1)*128;
            #pragma unroll
            for (int t = 0; t < 8; ++t) {
                f32x4 bv = *(const f32x4*)(bj + 16*t + 4*g);
                acc[0][t] = bv; acc[1][t] = bv;
            }
            const char* wb = smem + 32768;
            #pragma unroll
            for (int ks = 0; ks < 4; ++ks) {
                u32x4 u0 = {bfr[0][ks][0], bfr[0][ks][1], bfr[0][ks][2], bfr[0][ks][3]};
                u32x4 u1 = {bfr[1][ks][0], bfr[1][ks][1], bfr[1][ks][2], bfr[1][ks][3]};
                bf16x8 bf0 = __builtin_bit_cast(bf16x8, u0);
                bf16x8 bf1 = __builtin_bit_cast(bf16x8, u1);
                #pragma unroll
                for (int t = 0; t < 8; ++t) {
                    bf16x8 a = *(const bf16x8*)(wb + (16*t + l16)*256 + ((64*ks + 16*g) ^ swz));
                    acc[0][t] = __builtin_amdgcn_mfma_f32_16x16x32_bf16(a, bf0, acc[0][t], 0,0,0);
                    acc[1][t] = __builtin_amdgcn_mfma_f32_16x16x32_bf16(a, bf1, acc[1][t], 0,0,0);
                }
            }
        }
        // epilogue2: resid = w2*(resid + sin(acc)), f32 in registers
        const float w2 = (blk == NB-1) ? 0.5f : 1.0f;
        #pragma unroll
        for (int s = 0; s < 2; ++s)
            #pragma unroll
            for (int t = 0; t < 8; ++t)
                #pragma unroll
                for (int r = 0; r < 4; ++r)
                    resid[s][t][r] = w2 * (resid[s][t][r] + sin_rev(acc[s][t][r]));
        // write staged matrix into buf0
        if (blk < NB-1) {
            u32x4* lp = (u32x4*)smem;
            #pragma unroll
            for (int i = 0; i < 4; ++i) lp[w*256 + i*64 + lane] = st[i];
        }
        __syncthreads();
    }

    // ---- final linear: out = resid @ Wf^T + bf (reduce over 4 g-groups) ----
    #pragma unroll
    for (int s = 0; s < 2; ++s) {
        float part = 0.f;
        #pragma unroll
        for (int t = 0; t < 8; ++t) {
            f32x4 wv = *(const f32x4*)(Wf + 16*t + 4*g);
            part += resid[s][t][0]*wv[0] + resid[s][t][1]*wv[1]
                  + resid[s][t][2]*wv[2] + resid[s][t][3]*wv[3];
        }
        part += __shfl_xor(part, 16);
        part += __shfl_xor(part, 32);
        if (g == 0) out[ptb + 16*s + l16] = part + bfin[0];
    }
}

extern "C" void kernel_launch(void* const* d_in, const int* in_sizes, int n_in,
                              void* d_out, int out_size, void* d_ws, size_t ws_size,
                              hipStream_t stream) {
    const float* x   = (const float*)d_in[0];
    const float* W0  = (const float*)d_in[1];
    const float* b0  = (const float*)d_in[2];
    const float* Wa  = (const float*)d_in[3];
    const float* ba  = (const float*)d_in[4];
    const float* Wb  = (const float*)d_in[5];
    const float* bb  = (const float*)d_in[6];
    const float* Wf  = (const float*)d_in[7];
    const float* bf_ = (const float*)d_in[8];

    prep<<<dim3(903), dim3(256), 0, stream>>>(Wa, ba, Wb, bb);
    hipFuncSetAttribute(reinterpret_cast<const void*>(siren_mlp),
                        hipFuncAttributeMaxDynamicSharedMemorySize, LDS_BYTES);
    siren_mlp<<<dim3(NPTS/256), dim3(512), LDS_BYTES, stream>>>(
        x, W0, b0, Wf, bf_, (float*)d_out);
}

// Round 4
// 148.794 us; speedup vs baseline: 2.3514x; 1.0268x over previous
//
#include <hip/hip_runtime.h>

// SIREN fused MLP, v4: v2's PROVEN staging/barrier skeleton (single st[4],
// write-before-barrier, no unroll pragma, no setprio) + JIT-interleaved
// epilogues: the B-fragment for MFMA k-step ks depends only on acc[t=2ks,2ks+1]
// of the previous matmul, so sin/cvt_pk (and the residual update) run per-ks
// BETWEEN MFMA clusters -> VALU overlaps MFMA/LDS within each wave.
#define NPTS 262144
#define HID  128
#define NB   7
#define NMAT 14

typedef __attribute__((ext_vector_type(8))) short bf16x8;
typedef __attribute__((ext_vector_type(4))) float f32x4;
typedef __attribute__((ext_vector_type(4))) unsigned int u32x4;

constexpr float OMEGA  = 30.0f;
constexpr float INV2PI = 0.15915494309189535f;

#define WIMG_BYTES (NMAT*32768)   // 458752
#define BIAS_ELEMS (NMAT*128)     // 1792 f32, prescaled
__device__ __align__(16) unsigned char g_img[WIMG_BYTES + BIAS_ELEMS*4];

__device__ __forceinline__ unsigned short f2bf(float v) {
    unsigned int u = __float_as_uint(v);
    u += 0x7fffu + ((u >> 16) & 1u);          // RNE
    return (unsigned short)(u >> 16);
}

__device__ __forceinline__ float sin_rev(float r) {
    // sin(2*pi*r): v_fract (exact periodic reduce) + v_sin (revolutions)
    return __builtin_amdgcn_sinf(__builtin_amdgcn_fractf(r));
}

__device__ __forceinline__ unsigned int cvtpk(float lo, float hi) {
    unsigned int r;
    asm("v_cvt_pk_bf16_f32 %0, %1, %2" : "=v"(r) : "v"(lo), "v"(hi));
    return r;
}

// ---- prep: bake scaled/permuted/swizzled bf16 weight image + biases ----
__global__ void prep(const float* __restrict__ Wa, const float* __restrict__ ba,
                     const float* __restrict__ Wb, const float* __restrict__ bb) {
    int idx = blockIdx.x * 256 + threadIdx.x;
    const float bscale = OMEGA * INV2PI;
    const int total = NMAT * HID * HID;
    if (idx < total) {
        int mi = idx >> 14, rc = idx & 16383;
        int row = rc >> 7, col = rc & 127;
        int l = mi >> 1;
        float sc = bscale, v;
        if (mi & 1) v = Wb[l*16384 + rc];
        else { v = Wa[l*16384 + rc]; if (l > 0) sc *= 0.5f; }   // w1=0.5, blk>0
        int t = col >> 4, g = (col >> 2) & 3, r = col & 3;
        int kp = ((t >> 1) << 5) | (g << 3) | ((t & 1) << 2) | r;
        int byte = mi*32768 + row*256 + ((kp*2) ^ ((row & 7) << 4));
        *(unsigned short*)(g_img + byte) = f2bf(v * sc);
    } else if (idx < total + BIAS_ELEMS) {
        int e = idx - total;
        int j = e >> 7, f = e & 127, l = j >> 1;
        float v = (j & 1) ? bb[l*HID + f] : ba[l*HID + f];
        ((float*)(g_img + WIMG_BYTES))[e] = v * bscale;
    }
}

// ---- main: 8 waves x 32 pts = 256 pts/block; LDS = Wdbuf(64K)+bias(7K) ----
#define LDS_BYTES 72704

__launch_bounds__(512, 1)
__global__ void siren_mlp(const float* __restrict__ x,
                          const float* __restrict__ W0,
                          const float* __restrict__ b0,
                          const float* __restrict__ Wf,
                          const float* __restrict__ bfin,
                          float* __restrict__ out) {
    extern __shared__ char smem[];          // buf0 @0, buf1 @32768, bsc @65536
    float* bsc = (float*)(smem + 65536);

    const int tid  = threadIdx.x;
    const int lane = tid & 63;
    const int w    = tid >> 6;
    const int l16  = lane & 15;
    const int g    = lane >> 4;
    const int swz  = (l16 & 7) << 4;
    const int ptb  = blockIdx.x * 256 + w * 32;
    const float bscale = OMEGA * INV2PI;

    // ---- prologue (v2 layout): issue Wa[0] + biases only ----
    u32x4 st[4];
    {
        const u32x4* gp = (const u32x4*)(g_img);
        #pragma unroll
        for (int i = 0; i < 4; ++i) st[i] = gp[w*256 + i*64 + lane];
    }
    u32x4 bld;
    if (tid < 448) bld = ((const u32x4*)(g_img + WIMG_BYTES))[tid];

    // ---- first layer: h = sin(omega*(x@W0^T+b0)), f32 VALU, acc-order ----
    f32x4 resid[2][8];
    #pragma unroll
    for (int s = 0; s < 2; ++s) {
        int pt = ptb + 16*s + l16;
        float x0 = x[3*pt], x1 = x[3*pt+1], x2 = x[3*pt+2];
        #pragma unroll
        for (int t = 0; t < 8; ++t)
            #pragma unroll
            for (int r = 0; r < 4; ++r) {
                int f = 16*t + 4*g + r;
                float arg = (x0*W0[3*f] + x1*W0[3*f+1] + x2*W0[3*f+2] + b0[f]) * bscale;
                resid[s][t][r] = sin_rev(arg);
            }
    }
    {
        u32x4* lp = (u32x4*)smem;
        #pragma unroll
        for (int i = 0; i < 4; ++i) lp[w*256 + i*64 + lane] = st[i];
        if (tid < 448) ((u32x4*)bsc)[tid] = bld;
    }
    __syncthreads();

    f32x4 acc1[2][8], acc2[2][8];
    // acc2 = 0 so blk-0's JIT residual update adds sin(0) == 0 (branch-free)
    #pragma unroll
    for (int s = 0; s < 2; ++s)
        #pragma unroll
        for (int t = 0; t < 8; ++t) acc2[s][t] = (f32x4){0.f, 0.f, 0.f, 0.f};

    for (int blk = 0; blk < NB; ++blk) {
        // v2 timing: issue Wb[blk] loads (in flight during matmul1)
        {
            const u32x4* gq = (const u32x4*)(g_img + (2*blk+1)*32768);
            #pragma unroll
            for (int i = 0; i < 4; ++i) st[i] = gq[w*256 + i*64 + lane];
        }

        // ---- matmul1: acc1 = b' + Wa'·h  (A from buf0), JIT pack ----
        {
            const float* bj = bsc + (2*blk)*128;
            #pragma unroll
            for (int t = 0; t < 8; ++t) {
                f32x4 bv = *(const f32x4*)(bj + 16*t + 4*g);
                acc1[0][t] = bv; acc1[1][t] = bv;
            }
            const char* wb = smem;
            #pragma unroll
            for (int ks = 0; ks < 4; ++ks) {
                unsigned int pk[2][4];
                // JIT: finish prev matmul2 epilogue for t=2ks,2ks+1, then pack
                #pragma unroll
                for (int s = 0; s < 2; ++s)
                    #pragma unroll
                    for (int tt = 0; tt < 2; ++tt) {
                        int t = 2*ks + tt;
                        #pragma unroll
                        for (int r = 0; r < 4; ++r)
                            resid[s][t][r] += sin_rev(acc2[s][t][r]);
                        pk[s][tt*2]   = cvtpk(resid[s][t][0], resid[s][t][1]);
                        pk[s][tt*2+1] = cvtpk(resid[s][t][2], resid[s][t][3]);
                    }
                u32x4 u0 = {pk[0][0], pk[0][1], pk[0][2], pk[0][3]};
                u32x4 u1 = {pk[1][0], pk[1][1], pk[1][2], pk[1][3]};
                bf16x8 bf0 = __builtin_bit_cast(bf16x8, u0);
                bf16x8 bf1 = __builtin_bit_cast(bf16x8, u1);
                #pragma unroll
                for (int t = 0; t < 8; ++t) {
                    bf16x8 a = *(const bf16x8*)(wb + (16*t + l16)*256 + ((64*ks + 16*g) ^ swz));
                    acc1[0][t] = __builtin_amdgcn_mfma_f32_16x16x32_bf16(a, bf0, acc1[0][t], 0,0,0);
                    acc1[1][t] = __builtin_amdgcn_mfma_f32_16x16x32_bf16(a, bf1, acc1[1][t], 0,0,0);
                }
            }
        }
        // v2 timing: write Wb[blk] -> buf1 BEFORE the barrier
        {
            u32x4* lq = (u32x4*)(smem + 32768);
            #pragma unroll
            for (int i = 0; i < 4; ++i) lq[w*256 + i*64 + lane] = st[i];
        }
        __syncthreads();
        // v2 timing: issue Wa[blk+1] loads (in flight during matmul2)
        if (blk < NB-1) {
            const u32x4* gp = (const u32x4*)(g_img + (2*blk+2)*32768);
            #pragma unroll
            for (int i = 0; i < 4; ++i) st[i] = gp[w*256 + i*64 + lane];
        }

        // ---- matmul2: acc2 = b' + Wb'·sin(acc1)  (A from buf1), JIT pack ----
        {
            const float* bj = bsc + (2*blk+1)*128;
            #pragma unroll
            for (int t = 0; t < 8; ++t) {
                f32x4 bv = *(const f32x4*)(bj + 16*t + 4*g);
                acc2[0][t] = bv; acc2[1][t] = bv;
            }
            const char* wb = smem + 32768;
            #pragma unroll
            for (int ks = 0; ks < 4; ++ks) {
                unsigned int pk[2][4];
                #pragma unroll
                for (int s = 0; s < 2; ++s)
                    #pragma unroll
                    for (int tt = 0; tt < 2; ++tt) {
                        int t = 2*ks + tt;
                        float v0 = sin_rev(acc1[s][t][0]);
                        float v1 = sin_rev(acc1[s][t][1]);
                        float v2 = sin_rev(acc1[s][t][2]);
                        float v3 = sin_rev(acc1[s][t][3]);
                        pk[s][tt*2]   = cvtpk(v0, v1);
                        pk[s][tt*2+1] = cvtpk(v2, v3);
                    }
                u32x4 u0 = {pk[0][0], pk[0][1], pk[0][2], pk[0][3]};
                u32x4 u1 = {pk[1][0], pk[1][1], pk[1][2], pk[1][3]};
                bf16x8 bf0 = __builtin_bit_cast(bf16x8, u0);
                bf16x8 bf1 = __builtin_bit_cast(bf16x8, u1);
                #pragma unroll
                for (int t = 0; t < 8; ++t) {
                    bf16x8 a = *(const bf16x8*)(wb + (16*t + l16)*256 + ((64*ks + 16*g) ^ swz));
                    acc2[0][t] = __builtin_amdgcn_mfma_f32_16x16x32_bf16(a, bf0, acc2[0][t], 0,0,0);
                    acc2[1][t] = __builtin_amdgcn_mfma_f32_16x16x32_bf16(a, bf1, acc2[1][t], 0,0,0);
                }
            }
        }
        // v2 timing: write Wa[blk+1] -> buf0 BEFORE the end barrier
        if (blk < NB-1) {
            u32x4* lp = (u32x4*)smem;
            #pragma unroll
            for (int i = 0; i < 4; ++i) lp[w*256 + i*64 + lane] = st[i];
        }
        __syncthreads();
    }

    // ---- tail: last residual update (w2=0.5) + final linear ----
    #pragma unroll
    for (int s = 0; s < 2; ++s) {
        float part = 0.f;
        #pragma unroll
        for (int t = 0; t < 8; ++t) {
            f32x4 wv = *(const f32x4*)(Wf + 16*t + 4*g);
            #pragma unroll
            for (int r = 0; r < 4; ++r) {
                float hn = 0.5f * (resid[s][t][r] + sin_rev(acc2[s][t][r]));
                part += hn * wv[r];
            }
        }
        part += __shfl_xor(part, 16);
        part += __shfl_xor(part, 32);
        if (g == 0) out[ptb + 16*s + l16] = part + bfin[0];
    }
}

extern "C" void kernel_launch(void* const* d_in, const int* in_sizes, int n_in,
                              void* d_out, int out_size, void* d_ws, size_t ws_size,
                              hipStream_t stream) {
    const float* x   = (const float*)d_in[0];
    const float* W0  = (const float*)d_in[1];
    const float* b0  = (const float*)d_in[2];
    const float* Wa  = (const float*)d_in[3];
    const float* ba  = (const float*)d_in[4];
    const float* Wb  = (const float*)d_in[5];
    const float* bb  = (const float*)d_in[6];
    const float* Wf  = (const float*)d_in[7];
    const float* bf_ = (const float*)d_in[8];

    prep<<<dim3(903), dim3(256), 0, stream>>>(Wa, ba, Wb, bb);
    hipFuncSetAttribute(reinterpret_cast<const void*>(siren_mlp),
                        hipFuncAttributeMaxDynamicSharedMemorySize, LDS_BYTES);
    siren_mlp<<<dim3(NPTS/256), dim3(512), LDS_BYTES, stream>>>(
        x, W0, b0, Wf, bf_, (float*)d_out);
}